// Round 5
// baseline (540.892 us; speedup 1.0000x reference)
//
#include <hip/hip_runtime.h>
#include <hip/hip_bf16.h>

#define B_ 4
#define S_ 2048
#define E_ 1024
#define H_ 8
#define D_ 128

using f16x8 = __attribute__((ext_vector_type(8))) _Float16;
using f32x4 = __attribute__((ext_vector_type(4))) float;

__device__ __forceinline__ ushort f2h_bits(float f) {
    union { _Float16 h; ushort u; } cv; cv.h = (_Float16)f; return cv.u;
}
__device__ __forceinline__ float h2f(ushort u) {
    union { ushort u; _Float16 h; } cv; cv.u = u; return (float)cv.h;
}

// load 8 contiguous fp32, convert to f16x8 A/B-frag (RNE via v_cvt_f16_f32)
__device__ __forceinline__ f16x8 pack8(const float* __restrict__ p) {
    float4 f0 = *(const float4*)p;
    float4 f1 = *(const float4*)(p + 4);
    f16x8 r;
    r[0] = (_Float16)f0.x; r[1] = (_Float16)f0.y;
    r[2] = (_Float16)f0.z; r[3] = (_Float16)f0.w;
    r[4] = (_Float16)f1.x; r[5] = (_Float16)f1.y;
    r[6] = (_Float16)f1.z; r[7] = (_Float16)f1.w;
    return r;
}

// ---------------- K/V projection ----------------
// grid: (B*S/128, H), block 256. A-frags and W-frags direct from global fp32
// (W is L2-resident), fp16 convert in-register. out layout: [B, H, S, D] fp16
__global__ __launch_bounds__(256) void kv_proj(
    const float* __restrict__ seq,
    const float* __restrict__ Wk, const float* __restrict__ Wv,
    const float* __restrict__ bk, const float* __restrict__ bv,
    ushort* __restrict__ ko, ushort* __restrict__ vo)
{
    const int m0 = blockIdx.x * 128, h = blockIdx.y;
    const int tid = threadIdx.x, lane = tid & 63, w = tid >> 6;
    const int l16 = lane & 15, quad = lane >> 4;

    // A-frags: A[m=lane&15][k=quad*8+j]
    f16x8 a[2][4];
    #pragma unroll
    for (int mt = 0; mt < 2; ++mt)
        #pragma unroll
        for (int ks = 0; ks < 4; ++ks)
            a[mt][ks] = pack8(&seq[(size_t)(m0 + w * 32 + mt * 16 + l16) * E_
                                   + h * D_ + ks * 32 + quad * 8]);

    const float* Ws[2]   = {Wk, Wv};
    const float* bs[2]   = {bk, bv};
    ushort*      outs[2] = {ko, vo};

    #pragma unroll
    for (int t = 0; t < 2; ++t) {
        const float* W = Ws[t] + (size_t)h * D_ * D_;
        f32x4 acc[2][8];
        #pragma unroll
        for (int mt = 0; mt < 2; ++mt)
            #pragma unroll
            for (int nt = 0; nt < 8; ++nt) { f32x4 z = {0.f,0.f,0.f,0.f}; acc[mt][nt] = z; }

        #pragma unroll
        for (int ks = 0; ks < 4; ++ks) {
            #pragma unroll
            for (int nt = 0; nt < 8; ++nt) {
                // B[k][n] = W[o=n][d=k]: read W row n at cols k (A-frag pattern)
                f16x8 bfr = pack8(&W[(size_t)(nt * 16 + l16) * D_ + ks * 32 + quad * 8]);
                #pragma unroll
                for (int mt = 0; mt < 2; ++mt)
                    acc[mt][nt] = __builtin_amdgcn_mfma_f32_16x16x32_f16(
                        a[mt][ks], bfr, acc[mt][nt], 0, 0, 0);
            }
        }

        #pragma unroll
        for (int nt = 0; nt < 8; ++nt) {
            int o = nt * 16 + l16;
            float bias = bs[t][h * D_ + o];
            #pragma unroll
            for (int mt = 0; mt < 2; ++mt)
                #pragma unroll
                for (int r = 0; r < 4; ++r) {
                    int m = m0 + w * 32 + mt * 16 + quad * 4 + r;
                    int bi = m >> 11, s = m & (S_ - 1);
                    outs[t][(((size_t)bi * H_ + h) * S_ + s) * D_ + o] =
                        f2h_bits(acc[mt][nt][r] + bias);
                }
        }
    }
}

// ---------------- Flash attention (Q computed on the fly) ----------------
// grid: (S/128, H, B), block 256 (4 waves, 32 Q-rows each)
__global__ __launch_bounds__(256) void attn(
    const float* __restrict__ seq, const float* __restrict__ Wq,
    const float* __restrict__ bq,
    const ushort* __restrict__ k, const ushort* __restrict__ v,
    float* __restrict__ out)
{
    constexpr int KSTR = 136;  // K tile [64][128] + 8 pad
    constexpr int VSTR = 72;   // Vt tile [128][64] + 8 pad
    constexpr int PSTR = 72;   // P tile [128][64] + 8 pad
    constexpr int QSTR = 136;  // Q tile [128][136] elems, aliases Klds+Vt (phase 0 only)
    __shared__ alignas(16) ushort smem[64 * KSTR + 128 * VSTR + 128 * PSTR]; // 54272 B
    ushort* const Klds = smem;                          // [64][136]
    ushort* const Vt   = smem + 64 * KSTR;              // [128][72]
    ushort* const Plds = smem + 64 * KSTR + 128 * VSTR; // [128][72]
    ushort* const Qlds = smem;                          // 128*136=17408 elems <= 17920

    const int m0 = blockIdx.x * 128;
    const int h = blockIdx.y, bi = blockIdx.z;
    const int bh = bi * H_ + h;
    const int tid = threadIdx.x, lane = tid & 63, w = tid >> 6;
    const int l16 = lane & 15, quad = lane >> 4;
    const size_t base = (size_t)bh * S_ * D_;
    const float qscale = 0.35355339059327373f * 1.4426950408889634f; // 1/sqrt(8)*log2(e)

    // ---- Phase 0: Q tile = X @ Wq^T + bq, pre-scaled, into registers via LDS ----
    {
        f16x8 xa[2][4];
        #pragma unroll
        for (int mt = 0; mt < 2; ++mt)
            #pragma unroll
            for (int ks = 0; ks < 4; ++ks)
                xa[mt][ks] = pack8(&seq[((size_t)bi * S_ + m0 + w * 32 + mt * 16 + l16) * E_
                                        + h * D_ + ks * 32 + quad * 8]);
        f32x4 qacc[2][8];
        #pragma unroll
        for (int mt = 0; mt < 2; ++mt)
            #pragma unroll
            for (int nt = 0; nt < 8; ++nt) { f32x4 z = {0.f,0.f,0.f,0.f}; qacc[mt][nt] = z; }

        const float* W = Wq + (size_t)h * D_ * D_;
        #pragma unroll
        for (int ks = 0; ks < 4; ++ks) {
            #pragma unroll
            for (int nt = 0; nt < 8; ++nt) {
                f16x8 bfr = pack8(&W[(size_t)(nt * 16 + l16) * D_ + ks * 32 + quad * 8]);
                #pragma unroll
                for (int mt = 0; mt < 2; ++mt)
                    qacc[mt][nt] = __builtin_amdgcn_mfma_f32_16x16x32_f16(
                        xa[mt][ks], bfr, qacc[mt][nt], 0, 0, 0);
            }
        }
        // C-layout rows (wave-private) -> Qlds, scaled+biased
        #pragma unroll
        for (int nt = 0; nt < 8; ++nt) {
            int o = nt * 16 + l16;
            float bias = bq[h * D_ + o];
            #pragma unroll
            for (int mt = 0; mt < 2; ++mt)
                #pragma unroll
                for (int r = 0; r < 4; ++r) {
                    int row = w * 32 + mt * 16 + quad * 4 + r;
                    Qlds[row * QSTR + o] = f2h_bits((qacc[mt][nt][r] + bias) * qscale);
                }
        }
    }
    __syncthreads();

    // Q A-frags (wave-private rows)
    f16x8 qf[2][4];
    #pragma unroll
    for (int mt = 0; mt < 2; ++mt)
        #pragma unroll
        for (int ks = 0; ks < 4; ++ks)
            qf[mt][ks] = *(const f16x8*)&Qlds[(w * 32 + mt * 16 + l16) * QSTR
                                              + ks * 32 + quad * 8];

    f32x4 o_acc[2][8];
    #pragma unroll
    for (int mt = 0; mt < 2; ++mt)
        #pragma unroll
        for (int nt = 0; nt < 8; ++nt) { f32x4 z = {0.f,0.f,0.f,0.f}; o_acc[mt][nt] = z; }
    float m_prev[2][4], l_sum[2][4];
    #pragma unroll
    for (int mt = 0; mt < 2; ++mt)
        #pragma unroll
        for (int r = 0; r < 4; ++r) { m_prev[mt][r] = -1e30f; l_sum[mt][r] = 0.f; }

    for (int j = 0; j < S_ / 64; ++j) {
        const int n0 = j * 64;
        __syncthreads();   // prior Qlds/Klds/Vt reads done before restage
        // stage K [64][128] fp16
        #pragma unroll
        for (int i = 0; i < 4; ++i) {
            int idx = tid + i * 256;
            int r = idx >> 4, c8 = (idx & 15) * 8;
            *(uint4*)&Klds[r * KSTR + c8] =
                *(const uint4*)&k[base + (size_t)(n0 + r) * D_ + c8];
        }
        // stage V transposed: Vt[d][kk] = V[n0+kk][d]
        #pragma unroll
        for (int i = 0; i < 4; ++i) {
            int idx = tid + i * 256;
            int d = idx & 127, kb = idx >> 7;
            union { ushort u[8]; uint4 q; } tmp;
            #pragma unroll
            for (int jj = 0; jj < 8; ++jj)
                tmp.u[jj] = v[base + (size_t)(n0 + kb * 8 + jj) * D_ + d];
            *(uint4*)&Vt[d * VSTR + kb * 8] = tmp.q;
        }
        __syncthreads();

        // S = Q K^T (wave computes [32 x 64])
        f32x4 sacc[2][4];
        #pragma unroll
        for (int mt = 0; mt < 2; ++mt)
            #pragma unroll
            for (int nt = 0; nt < 4; ++nt) { f32x4 z = {0.f,0.f,0.f,0.f}; sacc[mt][nt] = z; }
        #pragma unroll
        for (int ks = 0; ks < 4; ++ks) {
            #pragma unroll
            for (int nt = 0; nt < 4; ++nt) {
                f16x8 kf = *(const f16x8*)&Klds[(nt * 16 + l16) * KSTR + ks * 32 + quad * 8];
                #pragma unroll
                for (int mt = 0; mt < 2; ++mt)
                    sacc[mt][nt] = __builtin_amdgcn_mfma_f32_16x16x32_f16(
                        qf[mt][ks], kf, sacc[mt][nt], 0, 0, 0);
            }
        }

        // online softmax in log2 domain (rows quad*4+r; 16-lane xor reductions)
        #pragma unroll
        for (int mt = 0; mt < 2; ++mt) {
            #pragma unroll
            for (int r = 0; r < 4; ++r) {
                float mx = fmaxf(fmaxf(sacc[mt][0][r], sacc[mt][1][r]),
                                 fmaxf(sacc[mt][2][r], sacc[mt][3][r]));
                #pragma unroll
                for (int d = 1; d < 16; d <<= 1)
                    mx = fmaxf(mx, __shfl_xor(mx, d));
                float mnew  = fmaxf(m_prev[mt][r], mx);
                float alpha = exp2f(m_prev[mt][r] - mnew);
                ushort u0 = f2h_bits(exp2f(sacc[mt][0][r] - mnew));
                ushort u1 = f2h_bits(exp2f(sacc[mt][1][r] - mnew));
                ushort u2 = f2h_bits(exp2f(sacc[mt][2][r] - mnew));
                ushort u3 = f2h_bits(exp2f(sacc[mt][3][r] - mnew));
                // accumulate l from the ROUNDED p values so numerator (fp16 P
                // via MFMA) and denominator see the same quantization
                float rs = (h2f(u0) + h2f(u1)) + (h2f(u2) + h2f(u3));
                #pragma unroll
                for (int d = 1; d < 16; d <<= 1)
                    rs += __shfl_xor(rs, d);
                l_sum[mt][r] = l_sum[mt][r] * alpha + rs;
                m_prev[mt][r] = mnew;
                #pragma unroll
                for (int nt = 0; nt < 8; ++nt)
                    o_acc[mt][nt][r] *= alpha;
                int prow = (w * 32 + mt * 16 + quad * 4 + r) * PSTR + l16;
                Plds[prow]      = u0;
                Plds[prow + 16] = u1;
                Plds[prow + 32] = u2;
                Plds[prow + 48] = u3;
            }
        }
        // P rows are wave-private: same-wave DS ops are in-order

        // O += P V
        #pragma unroll
        for (int ks = 0; ks < 2; ++ks) {
            f16x8 pa[2];
            #pragma unroll
            for (int mt = 0; mt < 2; ++mt)
                pa[mt] = *(const f16x8*)&Plds[(w * 32 + mt * 16 + l16) * PSTR + ks * 32 + quad * 8];
            #pragma unroll
            for (int nt = 0; nt < 8; ++nt) {
                f16x8 vf = *(const f16x8*)&Vt[(nt * 16 + l16) * VSTR + ks * 32 + quad * 8];
                #pragma unroll
                for (int mt = 0; mt < 2; ++mt)
                    o_acc[mt][nt] = __builtin_amdgcn_mfma_f32_16x16x32_f16(
                        pa[mt], vf, o_acc[mt][nt], 0, 0, 0);
            }
        }
    }

    // epilogue: O / l, write fp32 [B,S,E]
    #pragma unroll
    for (int mt = 0; mt < 2; ++mt)
        #pragma unroll
        for (int r = 0; r < 4; ++r) {
            float rinv = 1.0f / l_sum[mt][r];
            int srow = m0 + w * 32 + mt * 16 + quad * 4 + r;
            #pragma unroll
            for (int nt = 0; nt < 8; ++nt) {
                int col = nt * 16 + l16;
                out[((size_t)bi * S_ + srow) * E_ + h * D_ + col] =
                    o_acc[mt][nt][r] * rinv;
            }
        }
}

extern "C" void kernel_launch(void* const* d_in, const int* in_sizes, int n_in,
                              void* d_out, int out_size, void* d_ws, size_t ws_size,
                              hipStream_t stream) {
    const float* seq = (const float*)d_in[0];
    const float* Wq  = (const float*)d_in[1];
    const float* Wk  = (const float*)d_in[2];
    const float* Wv  = (const float*)d_in[3];
    const float* bq  = (const float*)d_in[4];
    const float* bk  = (const float*)d_in[5];
    const float* bv  = (const float*)d_in[6];

    const size_t per = (size_t)B_ * H_ * S_ * D_;      // 8M elements
    if (ws_size < 2 * per * sizeof(ushort)) return;    // need 32 MB
    ushort* kws = (ushort*)d_ws;
    ushort* vws = kws + per;

    kv_proj<<<dim3(B_ * S_ / 128, H_), 256, 0, stream>>>(
        seq, Wk, Wv, bk, bv, kws, vws);
    attn<<<dim3(S_ / 128, H_, B_), 256, 0, stream>>>(
        seq, Wq, bq, kws, vws, (float*)d_out);
}

// Round 6
// 309.558 us; speedup vs baseline: 1.7473x; 1.7473x over previous
//
#include <hip/hip_runtime.h>
#include <hip/hip_bf16.h>

#define B_ 4
#define S_ 2048
#define E_ 1024
#define H_ 8
#define D_ 128

using f16x8 = __attribute__((ext_vector_type(8))) _Float16;
using f32x4 = __attribute__((ext_vector_type(4))) float;

__device__ __forceinline__ ushort f2h_bits(float f) {
    union { _Float16 h; ushort u; } cv; cv.h = (_Float16)f; return cv.u;
}
__device__ __forceinline__ float h2f(ushort u) {
    union { ushort u; _Float16 h; } cv; cv.u = u; return (float)cv.h;
}
__device__ __forceinline__ f16x8 pack8(const float* __restrict__ p) {
    float4 f0 = *(const float4*)p;
    float4 f1 = *(const float4*)(p + 4);
    f16x8 r;
    r[0] = (_Float16)f0.x; r[1] = (_Float16)f0.y;
    r[2] = (_Float16)f0.z; r[3] = (_Float16)f0.w;
    r[4] = (_Float16)f1.x; r[5] = (_Float16)f1.y;
    r[6] = (_Float16)f1.z; r[7] = (_Float16)f1.w;
    return r;
}

// ---------------- K/V projection ----------------
// grid: (B*S/128, H), block 256.
// K out: [B,H,S,D] fp16. V out TRANSPOSED: [B,H,D,S] fp16.
// Epilogues repack through LDS for b128 coalesced global stores.
__global__ __launch_bounds__(256) void kv_proj(
    const float* __restrict__ seq,
    const float* __restrict__ Wk, const float* __restrict__ Wv,
    const float* __restrict__ bk, const float* __restrict__ bv,
    ushort* __restrict__ ko, ushort* __restrict__ vo)
{
    constexpr int TS = 136;
    __shared__ ushort Tk[128 * TS];   // [s_local][d]  (swizzled cols)
    __shared__ ushort Tv[128 * TS];   // [d][s_local]
    const int m0 = blockIdx.x * 128, h = blockIdx.y;
    const int tid = threadIdx.x, lane = tid & 63, w = tid >> 6;
    const int l16 = lane & 15, quad = lane >> 4;

    // A-frags: A[m=lane&15][k=quad*8+j]
    f16x8 a[2][4];
    #pragma unroll
    for (int mt = 0; mt < 2; ++mt)
        #pragma unroll
        for (int ks = 0; ks < 4; ++ks)
            a[mt][ks] = pack8(&seq[(size_t)(m0 + w * 32 + mt * 16 + l16) * E_
                                   + h * D_ + ks * 32 + quad * 8]);

    // ---- K ----
    {
        const float* W = Wk + (size_t)h * D_ * D_;
        f32x4 acc[2][8];
        #pragma unroll
        for (int mt = 0; mt < 2; ++mt)
            #pragma unroll
            for (int nt = 0; nt < 8; ++nt) { f32x4 z = {0.f,0.f,0.f,0.f}; acc[mt][nt] = z; }
        #pragma unroll
        for (int ks = 0; ks < 4; ++ks)
            #pragma unroll
            for (int nt = 0; nt < 8; ++nt) {
                f16x8 bfr = pack8(&W[(size_t)(nt * 16 + l16) * D_ + ks * 32 + quad * 8]);
                #pragma unroll
                for (int mt = 0; mt < 2; ++mt)
                    acc[mt][nt] = __builtin_amdgcn_mfma_f32_16x16x32_f16(
                        a[mt][ks], bfr, acc[mt][nt], 0, 0, 0);
            }
        #pragma unroll
        for (int nt = 0; nt < 8; ++nt) {
            int o = nt * 16 + l16;
            float bias = bk[h * D_ + o];
            #pragma unroll
            for (int mt = 0; mt < 2; ++mt)
                #pragma unroll
                for (int r = 0; r < 4; ++r) {
                    int row = w * 32 + mt * 16 + quad * 4 + r;
                    Tk[row * TS + (o ^ (quad << 3))] = f2h_bits(acc[mt][nt][r] + bias);
                }
        }
    }
    // ---- V ----
    {
        const float* W = Wv + (size_t)h * D_ * D_;
        f32x4 acc[2][8];
        #pragma unroll
        for (int mt = 0; mt < 2; ++mt)
            #pragma unroll
            for (int nt = 0; nt < 8; ++nt) { f32x4 z = {0.f,0.f,0.f,0.f}; acc[mt][nt] = z; }
        #pragma unroll
        for (int ks = 0; ks < 4; ++ks)
            #pragma unroll
            for (int nt = 0; nt < 8; ++nt) {
                f16x8 bfr = pack8(&W[(size_t)(nt * 16 + l16) * D_ + ks * 32 + quad * 8]);
                #pragma unroll
                for (int mt = 0; mt < 2; ++mt)
                    acc[mt][nt] = __builtin_amdgcn_mfma_f32_16x16x32_f16(
                        a[mt][ks], bfr, acc[mt][nt], 0, 0, 0);
            }
        #pragma unroll
        for (int nt = 0; nt < 8; ++nt) {
            int o = nt * 16 + l16;
            float bias = bv[h * D_ + o];
            #pragma unroll
            for (int mt = 0; mt < 2; ++mt)
                #pragma unroll
                for (int r = 0; r < 4; ++r) {
                    int row = w * 32 + mt * 16 + quad * 4 + r;
                    Tv[o * TS + row] = f2h_bits(acc[mt][nt][r] + bias);
                }
        }
    }
    __syncthreads();

    // coalesced b128 stores
    #pragma unroll
    for (int i = 0; i < 8; ++i) {
        int idx = tid + i * 256;
        int row = idx >> 4, c8 = (idx & 15) * 8;
        // K: logical [row][c8..c8+7] lives at swizzled chunk
        uint4 dk = *(uint4*)&Tk[row * TS + (c8 ^ (((row >> 2) & 3) << 3))];
        int m = m0 + row, bi = m >> 11, s = m & (S_ - 1);
        *(uint4*)&ko[(((size_t)bi * H_ + h) * S_ + s) * D_ + c8] = dk;
        // V: [d=row][s_local c8..c8+7]
        uint4 dv = *(uint4*)&Tv[row * TS + c8];
        int mg = m0 + c8, bv_i = mg >> 11, s0 = mg & (S_ - 1);
        *(uint4*)&vo[(((size_t)bv_i * H_ + h) * D_ + row) * S_ + s0] = dv;
    }
}

// ---------------- Flash attention ----------------
// grid: (S/128, H, B), block 256 (4 waves, 32 Q-rows each). BN = 128.
// LDS: K tile [128][136] (aliased by Q tile in phase 0 and by P each iter)
//      + Vt tile [128][136]  => 69632 B => 2 blocks/CU.
__global__ __launch_bounds__(256) void attn(
    const float* __restrict__ seq, const float* __restrict__ Wq,
    const float* __restrict__ bq,
    const ushort* __restrict__ kg, const ushort* __restrict__ vtg,
    float* __restrict__ out)
{
    constexpr int KS = 136;
    constexpr int VS = 136;
    __shared__ alignas(16) ushort smem[128 * KS + 128 * VS]; // 69632 B
    ushort* const Klds = smem;            // [128][136]; P and Q alias this
    ushort* const Vt   = smem + 128 * KS; // [d=128][s=128+pad]

    const int m0 = blockIdx.x * 128;
    const int h = blockIdx.y, bi = blockIdx.z;
    const int bh = bi * H_ + h;
    const int tid = threadIdx.x, lane = tid & 63, w = tid >> 6;
    const int l16 = lane & 15, quad = lane >> 4;
    const size_t baseK = (size_t)bh * S_ * D_;
    const size_t baseV = (size_t)bh * D_ * S_;
    const float qscale = 0.35355339059327373f * 1.4426950408889634f; // 1/sqrt(8)*log2e
    const int qq_r = (l16 >> 2) & 3;   // read-side swizzle for P/Q frag rows

    // ---- Phase 0: Q tile = X Wq^T + bq (scaled), via swizzled Q region ----
    {
        f16x8 xa[2][4];
        #pragma unroll
        for (int mt = 0; mt < 2; ++mt)
            #pragma unroll
            for (int ks = 0; ks < 4; ++ks)
                xa[mt][ks] = pack8(&seq[((size_t)bi * S_ + m0 + w * 32 + mt * 16 + l16) * E_
                                        + h * D_ + ks * 32 + quad * 8]);
        f32x4 qacc[2][8];
        #pragma unroll
        for (int mt = 0; mt < 2; ++mt)
            #pragma unroll
            for (int nt = 0; nt < 8; ++nt) { f32x4 z = {0.f,0.f,0.f,0.f}; qacc[mt][nt] = z; }
        const float* W = Wq + (size_t)h * D_ * D_;
        #pragma unroll
        for (int ks = 0; ks < 4; ++ks)
            #pragma unroll
            for (int nt = 0; nt < 8; ++nt) {
                f16x8 bfr = pack8(&W[(size_t)(nt * 16 + l16) * D_ + ks * 32 + quad * 8]);
                #pragma unroll
                for (int mt = 0; mt < 2; ++mt)
                    qacc[mt][nt] = __builtin_amdgcn_mfma_f32_16x16x32_f16(
                        xa[mt][ks], bfr, qacc[mt][nt], 0, 0, 0);
            }
        #pragma unroll
        for (int nt = 0; nt < 8; ++nt) {
            int o = nt * 16 + l16;
            float bias = bq[h * D_ + o];
            #pragma unroll
            for (int mt = 0; mt < 2; ++mt)
                #pragma unroll
                for (int r = 0; r < 4; ++r) {
                    int row = w * 32 + mt * 16 + quad * 4 + r;
                    Klds[row * KS + (o ^ (quad << 3))] =
                        f2h_bits((qacc[mt][nt][r] + bias) * qscale);
                }
        }
    }
    __syncthreads();

    f16x8 qf[2][4];
    #pragma unroll
    for (int mt = 0; mt < 2; ++mt)
        #pragma unroll
        for (int ks = 0; ks < 4; ++ks)
            qf[mt][ks] = *(const f16x8*)&Klds[(w * 32 + mt * 16 + l16) * KS
                                              + ks * 32 + ((quad ^ qq_r) << 3)];

    f32x4 o_acc[2][8];
    #pragma unroll
    for (int mt = 0; mt < 2; ++mt)
        #pragma unroll
        for (int nt = 0; nt < 8; ++nt) { f32x4 z = {0.f,0.f,0.f,0.f}; o_acc[mt][nt] = z; }
    float m_prev[2][4], l_lane[2][4];
    #pragma unroll
    for (int mt = 0; mt < 2; ++mt)
        #pragma unroll
        for (int r = 0; r < 4; ++r) { m_prev[mt][r] = -1e30f; l_lane[mt][r] = 0.f; }

    for (int j = 0; j < S_ / 128; ++j) {
        const int n0 = j * 128;
        __syncthreads();   // A: prior PV (and phase-0 qf) reads done
        // stage K [128][128] (unswizzled)
        #pragma unroll
        for (int i = 0; i < 8; ++i) {
            int idx = tid + i * 256;
            int r = idx >> 4, c8 = (idx & 15) * 8;
            *(uint4*)&Klds[r * KS + c8] =
                *(const uint4*)&kg[baseK + (size_t)(n0 + r) * D_ + c8];
        }
        // stage Vt [d=128][s=128] from pre-transposed global
        #pragma unroll
        for (int i = 0; i < 8; ++i) {
            int idx = tid + i * 256;
            int d = idx >> 4, c8 = (idx & 15) * 8;
            *(uint4*)&Vt[d * VS + c8] =
                *(const uint4*)&vtg[baseV + (size_t)d * S_ + n0 + c8];
        }
        __syncthreads();   // B

        // S = Q K^T (wave: [32 x 128])
        f32x4 sacc[2][8];
        #pragma unroll
        for (int mt = 0; mt < 2; ++mt)
            #pragma unroll
            for (int nt = 0; nt < 8; ++nt) { f32x4 z = {0.f,0.f,0.f,0.f}; sacc[mt][nt] = z; }
        #pragma unroll
        for (int ks = 0; ks < 4; ++ks)
            #pragma unroll
            for (int nt = 0; nt < 8; ++nt) {
                f16x8 kf = *(const f16x8*)&Klds[(nt * 16 + l16) * KS + ks * 32 + quad * 8];
                #pragma unroll
                for (int mt = 0; mt < 2; ++mt)
                    sacc[mt][nt] = __builtin_amdgcn_mfma_f32_16x16x32_f16(
                        qf[mt][ks], kf, sacc[mt][nt], 0, 0, 0);
            }

        // online softmax; p packed back into sacc as fp16 bits
        #pragma unroll
        for (int mt = 0; mt < 2; ++mt)
            #pragma unroll
            for (int r = 0; r < 4; ++r) {
                float mx = sacc[mt][0][r];
                #pragma unroll
                for (int nt = 1; nt < 8; ++nt) mx = fmaxf(mx, sacc[mt][nt][r]);
                #pragma unroll
                for (int d = 1; d < 16; d <<= 1)
                    mx = fmaxf(mx, __shfl_xor(mx, d));
                float mnew  = fmaxf(m_prev[mt][r], mx);
                float alpha = exp2f(m_prev[mt][r] - mnew);
                m_prev[mt][r] = mnew;
                float sumr = 0.f;
                #pragma unroll
                for (int nt = 0; nt < 8; ++nt) {
                    ushort u = f2h_bits(exp2f(sacc[mt][nt][r] - mnew));
                    sumr += h2f(u);  // denominator sees same quantization as numerator
                    sacc[mt][nt][r] = __uint_as_float((unsigned)u);
                }
                l_lane[mt][r] = l_lane[mt][r] * alpha + sumr;
                #pragma unroll
                for (int nt = 0; nt < 8; ++nt)
                    o_acc[mt][nt][r] *= alpha;
            }

        __syncthreads();   // C: all waves done reading Klds; P may overwrite
        // P writes (swizzled, conflict-free); rows are wave-private
        #pragma unroll
        for (int mt = 0; mt < 2; ++mt)
            #pragma unroll
            for (int r = 0; r < 4; ++r) {
                int row = w * 32 + mt * 16 + quad * 4 + r;
                #pragma unroll
                for (int nt = 0; nt < 8; ++nt) {
                    int col = nt * 16 + l16;
                    Klds[row * KS + (col ^ (quad << 3))] =
                        (ushort)__float_as_uint(sacc[mt][nt][r]);
                }
            }

        // O += P V  (pa from own rows — same-wave DS ordering suffices)
        #pragma unroll
        for (int ks = 0; ks < 4; ++ks) {
            f16x8 pa[2];
            #pragma unroll
            for (int mt = 0; mt < 2; ++mt)
                pa[mt] = *(const f16x8*)&Klds[(w * 32 + mt * 16 + l16) * KS
                                              + ks * 32 + ((quad ^ qq_r) << 3)];
            #pragma unroll
            for (int nt = 0; nt < 8; ++nt) {
                f16x8 vf = *(const f16x8*)&Vt[(nt * 16 + l16) * VS + ks * 32 + quad * 8];
                #pragma unroll
                for (int mt = 0; mt < 2; ++mt)
                    o_acc[mt][nt] = __builtin_amdgcn_mfma_f32_16x16x32_f16(
                        pa[mt], vf, o_acc[mt][nt], 0, 0, 0);
            }
        }
    }

    // epilogue: reduce l across the 16-lane row group, O/l, write fp32 [B,S,E]
    #pragma unroll
    for (int mt = 0; mt < 2; ++mt)
        #pragma unroll
        for (int r = 0; r < 4; ++r) {
            float l = l_lane[mt][r];
            #pragma unroll
            for (int d = 1; d < 16; d <<= 1)
                l += __shfl_xor(l, d);
            float rinv = 1.0f / l;
            int srow = m0 + w * 32 + mt * 16 + quad * 4 + r;
            #pragma unroll
            for (int nt = 0; nt < 8; ++nt) {
                int col = nt * 16 + l16;
                out[((size_t)bi * S_ + srow) * E_ + h * D_ + col] =
                    o_acc[mt][nt][r] * rinv;
            }
        }
}

extern "C" void kernel_launch(void* const* d_in, const int* in_sizes, int n_in,
                              void* d_out, int out_size, void* d_ws, size_t ws_size,
                              hipStream_t stream) {
    const float* seq = (const float*)d_in[0];
    const float* Wq  = (const float*)d_in[1];
    const float* Wk  = (const float*)d_in[2];
    const float* Wv  = (const float*)d_in[3];
    const float* bq  = (const float*)d_in[4];
    const float* bk  = (const float*)d_in[5];
    const float* bv  = (const float*)d_in[6];

    const size_t per = (size_t)B_ * H_ * S_ * D_;      // 8M elements
    if (ws_size < 2 * per * sizeof(ushort)) return;    // need 32 MB
    ushort* kws  = (ushort*)d_ws;          // [B,H,S,D]
    ushort* vtws = kws + per;              // [B,H,D,S] (transposed)

    kv_proj<<<dim3(B_ * S_ / 128, H_), 256, 0, stream>>>(
        seq, Wk, Wv, bk, bv, kws, vtws);
    attn<<<dim3(S_ / 128, H_, B_), 256, 0, stream>>>(
        seq, Wq, bq, kws, vtws, (float*)d_out);
}